// Round 8
// baseline (235.224 us; speedup 1.0000x reference)
//
#include <hip/hip_runtime.h>
#include <hip/hip_cooperative_groups.h>
#include <stdint.h>

namespace cg = cooperative_groups;

#define N_TOT 10647
#define MAXW  167        // ceil(10647/64)
#define NB    42         // ceil(10647/256) score tiles
#define NTP   (NB * NB)  // 1764 rank tile-pairs
#define NBD   167        // decode box-groups of 64
#define NCLS  80
#define ECAP  (1 << 20)  // edge buffer cap (4 MB); expected E ~ 1e3-1e4
#define GRID  256
#define BLK   256

typedef unsigned long long ull;

// YOLOv3 COCO anchors, grouped by head: [0..2]=13x13, [3..5]=26x26, [6..8]=52x52
__constant__ float c_aw[9] = {116.f,156.f,373.f, 30.f,62.f,59.f, 10.f,16.f,33.f};
__constant__ float c_ah[9] = { 90.f,198.f,326.f, 61.f,45.f,119.f, 13.f,30.f,23.f};

__device__ __forceinline__ float sigmoidf_(float x) { return 1.0f / (1.0f + expf(-x)); }

// misc layout: [0]=dV  [1]=ecnt  [2..81]=ccount  [82..161]=ccur
#define M_DV    0
#define M_ECNT  1
#define M_CNT   2
#define M_CUR   82
#define M_TOT   162

// One cooperative kernel, 7 phases separated by grid syncs.
__global__ void __launch_bounds__(BLK)
yolo_mega(const float* __restrict__ p0, const float* __restrict__ p1,
          const float* __restrict__ p2,
          float* box, float* conf, float* score, int* cls,
          int* rank42, int* order,
          float* sx1, float* sy1, float* sx2, float* sy2, float* sarea,
          int* scls, int* class_idx,
          int* misc, ull* keepw, uint32_t* edges, float* out)
{
    cg::grid_group grid = cg::this_grid();
    const int tid = threadIdx.x;
    const int bid = blockIdx.x;

    __shared__ float sbest[4][64];
    __shared__ int   sbi[4][64];
    __shared__ float s_tile[256];
    __shared__ int   s_hist[NCLS];
    __shared__ int   s_loff[NCLS];
    __shared__ float tx1[256], ty1[256], tx2[256], ty2[256], tar[256];
    __shared__ int   trk[256];
    __shared__ ull   kA[MAXW], kB[MAXW], sup[MAXW];
    __shared__ int   s_changed;

    // ---- Phase A: decode (4 threads/box; strict '>' keeps first-max-wins) ----
    if (bid == 0 && tid < M_TOT) misc[tid] = 0;   // zero dV/ecnt/ccount/ccur
    if (bid < NBD) {
        int sub  = tid >> 6;
        int lane = tid & 63;
        int n = bid * 64 + lane;
        bool inb = (n < N_TOT);
        const float* p; int H, base, lvl; float stride;
        int nn = inb ? n : 0;
        if (nn < 507)       { p = p0; H = 13; base = 0;    stride = 32.f; lvl = 0; }
        else if (nn < 2535) { p = p1; H = 26; base = 507;  stride = 16.f; lvl = 1; }
        else                { p = p2; H = 52; base = 2535; stride = 8.f;  lvl = 2; }
        int m   = nn - base;
        int HW  = H * H;
        int a   = m / HW;
        int rem = m - a * HW;
        const float* q = p + (size_t)(a * 85) * HW + rem;
        float best = -3.4e38f; int bi = 20 * sub;
        if (inb) {
            int c0 = 20 * sub;
            #pragma unroll 5
            for (int c = c0; c < c0 + 20; ++c) {
                float v = q[(size_t)(5 + c) * HW];
                if (v > best) { best = v; bi = c; }
            }
        }
        sbest[sub][lane] = best;
        sbi[sub][lane]   = bi;
        __syncthreads();
        if (sub == 0 && inb) {
            float b0 = sbest[0][lane]; int i0 = sbi[0][lane];
            #pragma unroll
            for (int s = 1; s < 4; ++s) {
                float bs = sbest[s][lane];
                if (bs > b0) { b0 = bs; i0 = sbi[s][lane]; }
            }
            int gy = rem / H;
            int gx = rem - gy * H;
            float tx = q[0];
            float ty = q[(size_t)HW];
            float tw = q[(size_t)2*HW];
            float th = q[(size_t)3*HW];
            float tc = q[(size_t)4*HW];
            float cx = (sigmoidf_(tx) + (float)gx) * stride;
            float cy = (sigmoidf_(ty) + (float)gy) * stride;
            // exp(t)*(anchor/stride)*stride == exp(t)*anchor exactly (stride pow2)
            float bw = expf(tw) * c_aw[lvl*3 + a];
            float bh = expf(th) * c_ah[lvl*3 + a];
            float cf = sigmoidf_(tc);
            box[n*4+0] = cx; box[n*4+1] = cy; box[n*4+2] = bw; box[n*4+3] = bh;
            conf[n] = cf;
            cls[n]  = i0;
            score[n] = (cf >= 0.5f) ? cf : -1.0f;
        }
    }
    grid.sync();   // s1

    // ---- Phase B: stable-descending rank partials (tile-pair grid-stride) ----
    for (int tp = bid; tp < NTP; tp += GRID) {
        int bx = tp / NB;
        int by = tp - bx * NB;
        __syncthreads();                      // protect s_tile from prev iter
        int jj = by * 256 + tid;
        s_tile[tid] = (jj < N_TOT) ? score[jj] : -2.0f;   // sentinel < all
        __syncthreads();
        int i = bx * 256 + tid;
        float si = (i < N_TOT) ? score[i] : -2.0f;
        if (i < N_TOT && si >= 0.0f) {
            int j0 = by * 256;
            int r = 0;
            #pragma unroll 8
            for (int t = 0; t < 256; ++t) {
                float sj = s_tile[t];
                r += (sj > si || (sj == si && (j0 + t) < i)) ? 1 : 0;
            }
            rank42[(size_t)by * N_TOT + i] = r;
        }
    }
    grid.sync();   // s2

    // ---- Phase C: sum partials, scatter order[r]=i, gather sorted arrays,
    //               count V and per-class histogram ----
    {
        int i = bid * BLK + tid;              // GRID*BLK = 65536 >= N_TOT
        if (i < N_TOT && score[i] >= 0.0f) {
            atomicAdd(&misc[M_DV], 1);
            atomicAdd(&misc[M_CNT + cls[i]], 1);
            int r = 0;
            #pragma unroll 6
            for (int s = 0; s < NB; ++s) r += rank42[(size_t)s * N_TOT + i];
            order[r] = i;
            float cx = box[i*4+0], cy = box[i*4+1], w = box[i*4+2], h = box[i*4+3];
            float hw = w * 0.5f, hh = h * 0.5f;
            sx1[r] = cx - hw; sy1[r] = cy - hh;
            sx2[r] = cx + hw; sy2[r] = cy + hh;
            sarea[r] = w * h;
            scls[r]  = cls[i];
        }
    }
    grid.sync();   // s3

    // ---- Phase D: per-block local prefix of the class histogram, then
    //               grid-stride bucket fill via global cursors ----
    if (tid < NCLS) s_hist[tid] = misc[M_CNT + tid];
    __syncthreads();
    if (tid == 0) {
        int off = 0;
        for (int c = 0; c < NCLS; ++c) { s_loff[c] = off; off += s_hist[c]; }
    }
    __syncthreads();
    {
        int V = misc[M_DV];
        for (int r = bid * BLK + tid; r < V; r += GRID * BLK) {
            int c = scls[r];
            int pos = atomicAdd(&misc[M_CUR + c], 1);
            class_idx[s_loff[c] + pos] = r;
        }
    }
    grid.sync();   // s4

    // ---- Phase E: per-class all-pairs IoU edges (blocks 0..79) ----
    if (bid < NCLS) {
        int c   = bid;
        int off = s_loff[c];                  // still valid in LDS
        int n   = s_hist[c];
        for (int abase = 0; abase < n; abase += 256) {
            int a = abase + tid;
            bool ain = (a < n);
            int ra = 0; float ax1=0, ay1=0, ax2=0, ay2=0, aar=0;
            if (ain) {
                ra  = class_idx[off + a];
                ax1 = sx1[ra]; ay1 = sy1[ra];
                ax2 = sx2[ra]; ay2 = sy2[ra];
                aar = sarea[ra];
            }
            for (int bbase = 0; bbase <= abase; bbase += 256) {
                int b = bbase + tid;
                if (b < n) {
                    int rb = class_idx[off + b];
                    tx1[tid] = sx1[rb]; ty1[tid] = sy1[rb];
                    tx2[tid] = sx2[rb]; ty2[tid] = sy2[rb];
                    tar[tid] = sarea[rb]; trk[tid] = rb;
                }
                __syncthreads();
                int blim = min(256, n - bbase);
                int tlim = (bbase == abase) ? min(tid, blim) : blim;
                if (ain) {
                    for (int t = 0; t < tlim; ++t) {
                        float xx1 = fmaxf(ax1, tx1[t]);
                        float yy1 = fmaxf(ay1, ty1[t]);
                        float xx2 = fminf(ax2, tx2[t]);
                        float yy2 = fminf(ay2, ty2[t]);
                        float w = fmaxf(xx2 - xx1, 0.0f);
                        float h = fmaxf(yy2 - yy1, 0.0f);
                        float inter = w * h;
                        float uni   = aar + tar[t] - inter;
                        float iou   = inter / fmaxf(uni, 1e-9f);
                        if (iou > 0.5f) {
                            int rb = trk[t];
                            uint32_t ii = (uint32_t)max(ra, rb);
                            uint32_t jj = (uint32_t)min(ra, rb);
                            int pos = atomicAdd(&misc[M_ECNT], 1);
                            if (pos < ECAP) edges[pos] = (ii << 16) | jj;
                        }
                    }
                }
                __syncthreads();
            }
        }
    }
    grid.sync();   // s5

    // ---- Phase F: sparse Jacobi fixpoint for greedy NMS (block 0 only).
    // keep_new[i] = valid[i] & !OR_{edges (j,i)} keep_prev[j]; zero-change
    // round == unique fixpoint == greedy (induction over index-ordered DAG);
    // depth-d nodes final after d+1 rounds; cap V+2 => exact. ----
    if (bid == 0) {
        int V = misc[M_DV];
        int W = (V + 63) >> 6;
        int E = min(misc[M_ECNT], ECAP);
        for (int w = tid; w < W; w += BLK) {
            int rem = V - (w << 6);
            kA[w] = (rem >= 64) ? ~0ull : ((1ull << rem) - 1ull);
        }
        ull* cur = kA;
        ull* nxt = kB;
        __syncthreads();
        for (int round = 0; round <= V + 2 && W > 0; ++round) {
            for (int w = tid; w < W; w += BLK) sup[w] = 0ull;
            if (tid == 0) s_changed = 0;
            __syncthreads();
            for (int e = tid; e < E; e += BLK) {
                uint32_t pk = edges[e];
                int j = pk & 0xFFFF;
                int i = pk >> 16;
                if ((cur[j >> 6] >> (j & 63)) & 1ull)
                    atomicOr(&sup[i >> 6], 1ull << (i & 63));
            }
            __syncthreads();
            for (int w = tid; w < W; w += BLK) {
                int rem = V - (w << 6);
                ull valid = (rem >= 64) ? ~0ull : ((1ull << rem) - 1ull);
                ull nk = valid & ~sup[w];
                nxt[w] = nk;
                if (nk != cur[w]) s_changed = 1;
            }
            __syncthreads();
            int ch = s_changed;
            __syncthreads();   // all read s_changed before next-round reset
            ull* t = cur; cur = nxt; nxt = t;
            if (!ch) break;
        }
        for (int w = tid; w < MAXW; w += BLK) keepw[w] = (w < W) ? cur[w] : 0ull;
    }
    grid.sync();   // s6

    // ---- Phase G: write all output rows (zeros unless kept) ----
    {
        int V = misc[M_DV];
        for (int r = bid * BLK + tid; r < N_TOT; r += GRID * BLK) {
            float v0=0.f,v1=0.f,v2=0.f,v3=0.f,v4=0.f,v5=0.f;
            if (r < V && ((keepw[r >> 6] >> (r & 63)) & 1ull)) {
                int i = order[r];
                v0 = box[i*4+0]; v1 = box[i*4+1]; v2 = box[i*4+2]; v3 = box[i*4+3];
                v4 = conf[i];    v5 = (float)cls[i];
            }
            out[r*6+0]=v0; out[r*6+1]=v1; out[r*6+2]=v2;
            out[r*6+3]=v3; out[r*6+4]=v4; out[r*6+5]=v5;
        }
    }
}

extern "C" void kernel_launch(void* const* d_in, const int* in_sizes, int n_in,
                              void* d_out, int out_size, void* d_ws, size_t ws_size,
                              hipStream_t stream) {
    const float* p0 = (const float*)d_in[0];
    const float* p1 = (const float*)d_in[1];
    const float* p2 = (const float*)d_in[2];
    float* out = (float*)d_out;
    char* ws = (char*)d_ws;
    const int N = N_TOT;

    float* box   = (float*)ws;           // 4N
    float* conf  = box + 4*N;            // N
    float* score = conf + N;             // N
    float* sx1   = score + N;            // N
    float* sy1   = sx1 + N;              // N
    float* sx2   = sy1 + N;              // N
    float* sy2   = sx2 + N;              // N
    float* sarea = sy2 + N;              // N
    int* cls       = (int*)(sarea + N);  // N
    int* order     = cls + N;            // N
    int* scls      = order + N;          // N
    int* class_idx = scls + N;           // N
    int* rank42    = class_idx + N;      // 42N ints = 1.79 MB
    int* misc      = rank42 + (size_t)NB*N;  // 162 ints
    ull* keepw     = (ull*)(((uintptr_t)(misc + M_TOT) + 7) & ~(uintptr_t)7); // 167 ull
    uint32_t* edges = (uint32_t*)(((uintptr_t)(keepw + MAXW) + 15) & ~(uintptr_t)15); // 4 MB

    void* args[] = {
        (void*)&p0, (void*)&p1, (void*)&p2,
        (void*)&box, (void*)&conf, (void*)&score, (void*)&cls,
        (void*)&rank42, (void*)&order,
        (void*)&sx1, (void*)&sy1, (void*)&sx2, (void*)&sy2, (void*)&sarea,
        (void*)&scls, (void*)&class_idx,
        (void*)&misc, (void*)&keepw, (void*)&edges, (void*)&out
    };
    hipLaunchCooperativeKernel((const void*)yolo_mega, dim3(GRID), dim3(BLK),
                               args, 0, stream);
}